// Round 6
// baseline (2559.480 us; speedup 1.0000x reference)
//
#include <hip/hip_runtime.h>
#include <hip/hip_fp16.h>

#define N_NODES 100000
#define N_EDGES 3200000
#define OUT_DIM 176
#define LN_EPS 1e-5f

typedef _Float16 h2 __attribute__((ext_vector_type(2)));

// Bucket sort parameters: bucket = row >> 9 (512 rows/bucket)
#define NBUCK 196
#define PC_BLOCKS 512
#define PC_CHUNK (N_EDGES / PC_BLOCKS)  // 6250
#define BP_CHUNK 4096
#define BP_BLOCKS ((N_EDGES + BP_CHUNK - 1) / BP_CHUNK)  // 782

// ---------------------------------------------------------------------------
// Pass A: per-bucket edge counts.
__global__ __launch_bounds__(256) void precount_kernel(
    const int* __restrict__ rows, int* __restrict__ gcount) {
  __shared__ int hist[NBUCK];
  for (int i = threadIdx.x; i < NBUCK; i += 256) hist[i] = 0;
  __syncthreads();
  const int e0 = blockIdx.x * PC_CHUNK;
  for (int e = e0 + threadIdx.x; e < e0 + PC_CHUNK; e += 256) {
    const int r = __builtin_nontemporal_load(rows + e);
    atomicAdd(&hist[r >> 9], 1);
  }
  __syncthreads();
  for (int i = threadIdx.x; i < NBUCK; i += 256)
    if (hist[i]) atomicAdd(&gcount[i], hist[i]);
}

// Exclusive scan of bucket counts -> bucket_base[197], cursor copy.
__global__ __launch_bounds__(256) void bucket_scan_kernel(
    const int* __restrict__ gcount, int* __restrict__ bucket_base,
    int* __restrict__ bucket_cursor) {
  __shared__ int sA[256], sB[256];
  const int t = threadIdx.x;
  int v = (t < NBUCK) ? gcount[t] : 0;
  sA[t] = v;
  __syncthreads();
  int* src = sA;
  int* dst = sB;
  for (int off = 1; off < 256; off <<= 1) {
    dst[t] = src[t] + ((t >= off) ? src[t - off] : 0);
    __syncthreads();
    int* tmp = src; src = dst; dst = tmp;
  }
  if (t < NBUCK) {
    const int excl = src[t] - v;
    bucket_base[t] = excl;
    bucket_cursor[t] = excl;
  }
  if (t == 0) bucket_base[NBUCK] = N_EDGES;
}

// ---------------------------------------------------------------------------
// Pass B: bucket the edges.
__global__ __launch_bounds__(256) void bucket_pass_kernel(
    const int* __restrict__ rows, const int* __restrict__ cols,
    const float* __restrict__ vals, int* __restrict__ bucket_cursor,
    int2* __restrict__ bucketed) {
  __shared__ int cnt[NBUCK], cur[NBUCK], gbase[NBUCK];
  for (int i = threadIdx.x; i < NBUCK; i += 256) {
    cnt[i] = 0;
    cur[i] = 0;
  }
  __syncthreads();

  const int e0 = blockIdx.x * BP_CHUNK;
  int r_[16], c_[16];
  float v_[16];
#pragma unroll
  for (int k = 0; k < 16; ++k) {
    const int e = e0 + threadIdx.x + k * 256;
    if (e < N_EDGES) {
      r_[k] = rows[e];
      c_[k] = cols[e];
      v_[k] = vals[e];
      atomicAdd(&cnt[r_[k] >> 9], 1);
    } else {
      r_[k] = -1;
    }
  }
  __syncthreads();

  for (int i = threadIdx.x; i < NBUCK; i += 256)
    gbase[i] = cnt[i] ? atomicAdd(&bucket_cursor[i], cnt[i]) : 0;
  __syncthreads();

#pragma unroll
  for (int k = 0; k < 16; ++k) {
    if (r_[k] >= 0) {
      const int b = r_[k] >> 9;
      const int lp = atomicAdd(&cur[b], 1);
      const int meta = c_[k] | ((r_[k] & 511) << 17);
      bucketed[gbase[b] + lp] = make_int2(meta, __float_as_int(v_[k]));
    }
  }
}

// ---------------------------------------------------------------------------
// Pass C: one block per bucket -> row_ptr + exact CSR order.
__global__ __launch_bounds__(512) void csr_build_kernel(
    const int2* __restrict__ bucketed, const int* __restrict__ bucket_base,
    int* __restrict__ row_ptr, int2* __restrict__ packed) {
  __shared__ int hist[512], cur[512], sA[512], sB[512];
  const int t = threadIdx.x;
  const int blk = blockIdx.x;
  const int base = bucket_base[blk];
  const int n = bucket_base[blk + 1] - base;

  hist[t] = 0;
  __syncthreads();
  for (int i = t; i < n; i += 512) {
    const int rlow = bucketed[base + i].x >> 17;
    atomicAdd(&hist[rlow], 1);
  }
  __syncthreads();

  sA[t] = hist[t];
  __syncthreads();
  int* src = sA;
  int* dst = sB;
  for (int off = 1; off < 512; off <<= 1) {
    dst[t] = src[t] + ((t >= off) ? src[t - off] : 0);
    __syncthreads();
    int* tmp = src; src = dst; dst = tmp;
  }
  const int excl = src[t] - hist[t];

  const int row0 = blk << 9;
  if (row0 + t < N_NODES) row_ptr[row0 + t] = base + excl;
  if (blk == NBUCK - 1 && t == 0) row_ptr[N_NODES] = N_EDGES;
  cur[t] = excl;
  __syncthreads();

  for (int i = t; i < n; i += 512) {
    const int2 m = bucketed[base + i];
    const int rlow = m.x >> 17;
    const int col = m.x & 0x1FFFF;
    const int p = atomicAdd(&cur[rlow], 1);
    packed[base + p] = make_int2(col, m.y);
  }
}

// ===========================================================================
// MEGA KERNEL: convert + wprep + 3x (spmm ; dense) in ONE dispatch.
// Round-5 accounting: ~170 us of the 536-us total was inter-dispatch launch
// overhead (~13 us x 13 dispatches). Phases keep the proven structures
// (v3 spmm loop, v4 gang-staged dense) as grid-stride device functions,
// separated by a device-scope software grid barrier (monotonic counter,
// agent-scope acq/rel). Co-residency guaranteed: grid sized from
// hipOccupancyMaxActiveBlocksPerMultiprocessor x 256 CUs, occupancy declared
// via __launch_bounds__(256, 8) (8 blocks/CU at <=64 VGPR).
// ===========================================================================

struct MegaArgs {
  const float* emb;
  float* out;
  __half* emb_h;
  const float* w1r[3];
  const float* w2r[3];
  __half* wt1[3];
  __half* wt2[3];
  const float* b1[3];
  const float* b2[3];
  const float* g1[3];
  const float* be1[3];
  const float* g2[3];
  const float* be2[3];
  const int* row_ptr;
  const long long* packed;
  __half* side_h;
  __half* ego1_h;
  __half* ego2_h;
  int* bar;
};

// Device-scope grid barrier: monotonic counter, one add per block per phase.
// Safe (no reset races): a block only reaches phase p+1's add after count
// >= nblocks*p, so increments are phase-ordered.
__device__ __forceinline__ void grid_barrier(int* cnt, int phase) {
  __syncthreads();
  if (threadIdx.x == 0) {
    __threadfence();  // publish this block's writes (device scope)
    __hip_atomic_fetch_add(cnt, 1, __ATOMIC_RELEASE, __HIP_MEMORY_SCOPE_AGENT);
    const int target = (int)gridDim.x * phase;
    while (__hip_atomic_load(cnt, __ATOMIC_ACQUIRE,
                             __HIP_MEMORY_SCOPE_AGENT) < target)
      __builtin_amdgcn_s_sleep(2);
    __threadfence();  // acquire all other blocks' writes
  }
  __syncthreads();
}

// ---- spmm phase (v3 structure): one wave per node, grid-stride ----
template <int DIN>
__device__ void dev_spmm(const __half* ego_h, const int* row_ptr,
                         const long long* packed, __half* side_out_h,
                         int lane, int waveId, int nwaves) {
  constexpr int LPH = DIN / 8;    // lanes per edge-row (16B fp16 chunks)
  constexpr int NGRP = 64 / LPH;  // edges concurrent

  const int li = lane % LPH;
  const int grp = lane / LPH;
  const uint4* ego8 = (const uint4*)ego_h;

  for (int node = waveId; node < N_NODES; node += nwaves) {
    const int start = row_ptr[node];
    const int end = row_ptr[node + 1];

    float s[8] = {0.f, 0.f, 0.f, 0.f, 0.f, 0.f, 0.f, 0.f};

    for (int base = start; base < end; base += 64) {
      const int idx = base + lane;
      long long m = 0;  // col=0, val=0 padding contributes 0
      if (idx < end) m = __builtin_nontemporal_load(packed + idx);
      const int mc = (int)m;
      const int mv = (int)(m >> 32);
      const int cnt = min(end - base, 64);
      const int kmax = (cnt + NGRP - 1) / NGRP;
      for (int k = 0; k < kmax; ++k) {
        const int src = k * NGRP + grp;
        const int c = __shfl(mc, src, 64);
        const float v = __int_as_float(__shfl(mv, src, 64));
        uint4 raw = ego8[(long)c * LPH + li];
        const __half2* hp = (const __half2*)&raw;
        const float2 f0 = __half22float2(hp[0]);
        const float2 f1 = __half22float2(hp[1]);
        const float2 f2 = __half22float2(hp[2]);
        const float2 f3 = __half22float2(hp[3]);
        s[0] += v * f0.x; s[1] += v * f0.y;
        s[2] += v * f1.x; s[3] += v * f1.y;
        s[4] += v * f2.x; s[5] += v * f2.y;
        s[6] += v * f3.x; s[7] += v * f3.y;
      }
    }

#pragma unroll
    for (int mask = LPH; mask < 64; mask <<= 1)
#pragma unroll
      for (int r = 0; r < 8; ++r) s[r] += __shfl_xor(s[r], mask, 64);

    if (grp == 0) {
      __half2 p0 = __floats2half2_rn(s[0], s[1]);
      __half2 p1 = __floats2half2_rn(s[2], s[3]);
      __half2 p2 = __floats2half2_rn(s[4], s[5]);
      __half2 p3 = __floats2half2_rn(s[6], s[7]);
      uint4 u;
      u.x = *(unsigned int*)&p0;
      u.y = *(unsigned int*)&p1;
      u.z = *(unsigned int*)&p2;
      u.w = *(unsigned int*)&p3;
      ((uint4*)side_out_h)[(long)node * LPH + li] = u;
    }
  }
}

// ---- dense phase (v4 structure): LDS gang staging, grid-stride ----
template <int DIN, int DOUT, int COL_OFF>
__device__ void dev_dense(const __half* ego_h, const __half* side_h,
                          const __half* w1t, const float* b1,
                          const __half* w2t, const float* b2,
                          const float* g1, const float* be1,
                          const float* g2, const float* be2,
                          __half* ego_h_out, float* out,
                          uint4 (*lds)[2][64], int lane, int w, int waveId,
                          int nwaves) {
  constexpr int CH = DIN / 8;      // uint4 chunks per node row
  constexpr int G = 64 / CH;       // nodes per staged gang
  constexpr int NPW = 64 / DOUT;   // nodes per dot pass
  constexpr int PASSES = G / NPW;  // dot passes per gang

  const int j = lane % DOUT;
  const int sub = lane / DOUT;
  const int sn = lane / CH;  // node-in-gang this lane stages
  const int sc = lane % CH;  // chunk-in-node this lane stages

  const uint4* w1u = (const uint4*)w1t;
  const uint4* w2u = (const uint4*)w2t;
  uint4 wraw1[CH], wraw2[CH];
#pragma unroll
  for (int q = 0; q < CH; ++q) {
    wraw1[q] = w1u[j * CH + q];
    wraw2[q] = w2u[j * CH + q];
  }
  const float bb1 = b1[j], bb2 = b2[j];
  const float gg1 = g1[j], gg2 = g2[j];
  const float bbe1 = be1[j], bbe2 = be2[j];

  const uint4* ego8 = (const uint4*)ego_h;
  const uint4* side8 = (const uint4*)side_h;
  const int ngangs = N_NODES / G;  // exact: 100000 % {8,16} == 0

  uint4 eR, sR;
  if (waveId < ngangs) {
    const size_t b = (size_t)(waveId * G + sn) * CH + sc;
    eR = ego8[b];
    sR = side8[b];
  }

  for (int gang = waveId; gang < ngangs; gang += nwaves) {
    uint4 xsU, xpU;
    {
      const h2* e2 = (const h2*)&eR;
      const h2* s2 = (const h2*)&sR;
      h2* xs2 = (h2*)&xsU;
      h2* xp2 = (h2*)&xpU;
#pragma unroll
      for (int r = 0; r < 4; ++r) {
        xs2[r] = e2[r] + s2[r];
        xp2[r] = e2[r] * s2[r];
      }
    }
    // prior gang's ds_reads fully retired before overwriting the slab
    asm volatile("s_waitcnt lgkmcnt(0)" ::: "memory");
    __builtin_amdgcn_sched_barrier(0);
    lds[w][0][lane] = xsU;
    lds[w][1][lane] = xpU;

    // prefetch next gang into the 8 staging VGPRs (no wait)
    const int gn = gang + nwaves;
    if (gn < ngangs) {
      const size_t b = (size_t)(gn * G + sn) * CH + sc;
      eR = ego8[b];
      sR = side8[b];
    }

    // ds_writes visible to all lanes of this wave before the reads
    asm volatile("s_waitcnt lgkmcnt(0)" ::: "memory");
    __builtin_amdgcn_sched_barrier(0);

#pragma unroll
    for (int p = 0; p < PASSES; ++p) {
      const int nin = p * NPW + sub;
      const int node = gang * G + nin;

      float a1a = bb1, a1b = 0.f, a2a = bb2, a2b = 0.f;
#pragma unroll
      for (int q = 0; q < CH; ++q) {
        uint4 xsq = lds[w][0][nin * CH + q];
        uint4 xpq = lds[w][1][nin * CH + q];
        const h2* xs2 = (const h2*)&xsq;
        const h2* xp2 = (const h2*)&xpq;
        const h2* wq1 = (const h2*)&wraw1[q];
        const h2* wq2 = (const h2*)&wraw2[q];
#pragma unroll
        for (int r = 0; r < 4; ++r) {
#if __has_builtin(__builtin_amdgcn_fdot2)
          if (q & 1) {
            a1b = __builtin_amdgcn_fdot2(xs2[r], wq1[r], a1b, false);
            a2b = __builtin_amdgcn_fdot2(xp2[r], wq2[r], a2b, false);
          } else {
            a1a = __builtin_amdgcn_fdot2(xs2[r], wq1[r], a1a, false);
            a2a = __builtin_amdgcn_fdot2(xp2[r], wq2[r], a2a, false);
          }
#else
          if (q & 1) {
            a1b += (float)xs2[r].x * (float)wq1[r].x +
                   (float)xs2[r].y * (float)wq1[r].y;
            a2b += (float)xp2[r].x * (float)wq2[r].x +
                   (float)xp2[r].y * (float)wq2[r].y;
          } else {
            a1a += (float)xs2[r].x * (float)wq1[r].x +
                   (float)xs2[r].y * (float)wq1[r].y;
            a2a += (float)xp2[r].x * (float)wq2[r].x +
                   (float)xp2[r].y * (float)wq2[r].y;
          }
#endif
        }
      }

      const float acc1 = a1a + a1b;
      const float acc2 = a2a + a2b;
      const float h1 = acc1 > 0.f ? acc1 : 0.01f * acc1;
      const float h2v = acc2 > 0.f ? acc2 : 0.01f * acc2;

      float s1 = h1, q1 = h1 * h1, s2 = h2v, q2 = h2v * h2v;
#pragma unroll
      for (int mask = DOUT / 2; mask > 0; mask >>= 1) {
        s1 += __shfl_xor(s1, mask, DOUT);
        q1 += __shfl_xor(q1, mask, DOUT);
        s2 += __shfl_xor(s2, mask, DOUT);
        q2 += __shfl_xor(q2, mask, DOUT);
      }
      const float m1 = s1 * (1.0f / DOUT);
      const float m2 = s2 * (1.0f / DOUT);
      const float v1 = fmaxf(q1 * (1.0f / DOUT) - m1 * m1, 0.f);
      const float v2 = fmaxf(q2 * (1.0f / DOUT) - m2 * m2, 0.f);
      const float sv = (h1 - m1) * rsqrtf(v1 + LN_EPS) * gg1 + bbe1;
      const float bv = (h2v - m2) * rsqrtf(v2 + LN_EPS) * gg2 + bbe2;
      const float en = sv + bv;

      float ss = en * en;
#pragma unroll
      for (int mask = DOUT / 2; mask > 0; mask >>= 1) {
        ss += __shfl_xor(ss, mask, DOUT);
      }
      const float ov = en / fmaxf(sqrtf(ss), 1e-12f);

      if (ego_h_out) ego_h_out[(long)node * DOUT + j] = __float2half(en);
      out[(long)node * OUT_DIM + COL_OFF + j] = ov;
    }
  }
}

__global__ __launch_bounds__(256, 8) void mega_kernel(MegaArgs a) {
  __shared__ uint4 lds[4][2][64];  // per-wave xs/xp gang slab (8 KB)

  const int lane = threadIdx.x & 63;
  const int w = threadIdx.x >> 6;
  const int tid = blockIdx.x * 256 + threadIdx.x;
  const int nthreads = (int)gridDim.x * 256;
  const int waveId = tid >> 6;
  const int nwaves = nthreads >> 6;

  // ---- phase 0: convert emb (out[:,0:64] + emb_h) and weight prep ----
  for (int t = tid; t < N_NODES * 16; t += nthreads) {
    const int n = t >> 4, q = t & 15;
    float4 v = ((const float4*)a.emb)[t];
    ((float4*)a.out)[n * 44 + q] = v;
    __half2 ha = __floats2half2_rn(v.x, v.y);
    __half2 hb = __floats2half2_rn(v.z, v.w);
    uint2 u;
    u.x = *(unsigned int*)&ha;
    u.y = *(unsigned int*)&hb;
    ((uint2*)a.emb_h)[t] = u;
  }
  for (int i0 = tid; i0 < 4096 + 2048 + 512; i0 += nthreads) {
    int idx = i0;
    const float* w1;
    const float* w2;
    __half* t1;
    __half* t2;
    int din, dout;
    if (idx < 4096) {
      w1 = a.w1r[0]; w2 = a.w2r[0]; t1 = a.wt1[0]; t2 = a.wt2[0];
      din = 64; dout = 64;
    } else if (idx < 4096 + 2048) {
      idx -= 4096;
      w1 = a.w1r[1]; w2 = a.w2r[1]; t1 = a.wt1[1]; t2 = a.wt2[1];
      din = 64; dout = 32;
    } else {
      idx -= 4096 + 2048;
      w1 = a.w1r[2]; w2 = a.w2r[2]; t1 = a.wt1[2]; t2 = a.wt2[2];
      din = 32; dout = 16;
    }
    const int i = idx / dout, jj = idx % dout;
    t1[jj * din + i] = __float2half(w1[idx]);
    t2[jj * din + i] = __float2half(w2[idx]);
  }
  grid_barrier(a.bar, 1);

  // ---- layer 0: 64 -> 64 ----
  dev_spmm<64>(a.emb_h, a.row_ptr, a.packed, a.side_h, lane, waveId, nwaves);
  grid_barrier(a.bar, 2);
  dev_dense<64, 64, 64>(a.emb_h, a.side_h, a.wt1[0], a.b1[0], a.wt2[0],
                        a.b2[0], a.g1[0], a.be1[0], a.g2[0], a.be2[0],
                        a.ego1_h, a.out, lds, lane, w, waveId, nwaves);
  grid_barrier(a.bar, 3);

  // ---- layer 1: 64 -> 32 ----
  dev_spmm<64>(a.ego1_h, a.row_ptr, a.packed, a.side_h, lane, waveId, nwaves);
  grid_barrier(a.bar, 4);
  dev_dense<64, 32, 128>(a.ego1_h, a.side_h, a.wt1[1], a.b1[1], a.wt2[1],
                         a.b2[1], a.g1[1], a.be1[1], a.g2[1], a.be2[1],
                         a.ego2_h, a.out, lds, lane, w, waveId, nwaves);
  grid_barrier(a.bar, 5);

  // ---- layer 2: 32 -> 16 ----
  dev_spmm<32>(a.ego2_h, a.row_ptr, a.packed, a.side_h, lane, waveId, nwaves);
  grid_barrier(a.bar, 6);
  dev_dense<32, 16, 160>(a.ego2_h, a.side_h, a.wt1[2], a.b1[2], a.wt2[2],
                         a.b2[2], a.g1[2], a.be1[2], a.g2[2], a.be2[2],
                         nullptr, a.out, lds, lane, w, waveId, nwaves);
}

// ---------------------------------------------------------------------------
extern "C" void kernel_launch(void* const* d_in, const int* in_sizes, int n_in,
                              void* d_out, int out_size, void* d_ws,
                              size_t ws_size, hipStream_t stream) {
  const float* emb = (const float*)d_in[0];
  const int* rows = (const int*)d_in[1];
  const int* cols = (const int*)d_in[2];
  const float* vals = (const float*)d_in[3];

  const float* P[3][8];
  for (int k = 0; k < 3; ++k)
    for (int p = 0; p < 8; ++p) P[k][p] = (const float*)d_in[4 + 8 * k + p];

  float* out = (float*)d_out;

  char* ws = (char*)d_ws;
  int2* packed = (int2*)ws;                   // E*8   = 25.6 MB
  char* sideArea = ws + (size_t)N_EDGES * 8;  // 25.6 MB region
  __half* side_h = (__half*)sideArea;         // N*64*2 = 12.8 MB used
  int2* bucketed = (int2*)sideArea;  // ALIAS: dead before spmm writes side
  __half* emb_h = (__half*)(sideArea + (size_t)N_NODES * 64 * 4);  // 12.8 MB
  __half* ego1_h = emb_h + (size_t)N_NODES * 64;                   // 12.8 MB
  __half* ego2_h = ego1_h + (size_t)N_NODES * 64;                  // 6.4 MB
  // transposed fp16 weights (16B-aligned block)
  __half* wt1_0 = ego2_h + (size_t)N_NODES * 32;  // 4096 halves
  __half* wt2_0 = wt1_0 + 4096;
  __half* wt1_1 = wt2_0 + 4096;  // 2048
  __half* wt2_1 = wt1_1 + 2048;
  __half* wt1_2 = wt2_1 + 2048;  // 512
  __half* wt2_2 = wt1_2 + 512;
  int* row_ptr = (int*)(wt2_2 + 512);  // N+1
  int* gcount = row_ptr + (N_NODES + 1);
  int* bar = gcount + NBUCK;  // barrier counter (zeroed with gcount)
  int* bucket_base = bar + 1;
  int* bucket_cursor = bucket_base + (NBUCK + 1);

  // ---- CSR build via two-level bucket sort ----
  hipMemsetAsync(gcount, 0, (NBUCK + 1) * sizeof(int), stream);  // + bar
  precount_kernel<<<PC_BLOCKS, 256, 0, stream>>>(rows, gcount);
  bucket_scan_kernel<<<1, 256, 0, stream>>>(gcount, bucket_base,
                                            bucket_cursor);
  bucket_pass_kernel<<<BP_BLOCKS, 256, 0, stream>>>(rows, cols, vals,
                                                    bucket_cursor, bucketed);
  csr_build_kernel<<<NBUCK, 512, 0, stream>>>(bucketed, bucket_base, row_ptr,
                                              packed);

  // ---- mega kernel: convert + wprep + 3x (spmm ; dense) ----
  MegaArgs a;
  a.emb = emb;
  a.out = out;
  a.emb_h = emb_h;
  a.w1r[0] = P[0][0]; a.w2r[0] = P[0][2];
  a.w1r[1] = P[1][0]; a.w2r[1] = P[1][2];
  a.w1r[2] = P[2][0]; a.w2r[2] = P[2][2];
  a.wt1[0] = wt1_0; a.wt2[0] = wt2_0;
  a.wt1[1] = wt1_1; a.wt2[1] = wt2_1;
  a.wt1[2] = wt1_2; a.wt2[2] = wt2_2;
  for (int k = 0; k < 3; ++k) {
    a.b1[k] = P[k][1];
    a.b2[k] = P[k][3];
    a.g1[k] = P[k][4];
    a.be1[k] = P[k][5];
    a.g2[k] = P[k][6];
    a.be2[k] = P[k][7];
  }
  a.row_ptr = row_ptr;
  a.packed = (const long long*)packed;
  a.side_h = side_h;
  a.ego1_h = ego1_h;
  a.ego2_h = ego2_h;
  a.bar = bar;

  // Grid sized for guaranteed co-residency (software grid barrier safety).
  int nbpc = 0;
  if (hipOccupancyMaxActiveBlocksPerMultiprocessor(&nbpc, mega_kernel, 256,
                                                   0) != hipSuccess ||
      nbpc < 1)
    nbpc = 4;  // conservative fallback (128-VGPR worst case)
  if (nbpc > 8) nbpc = 8;
  const int MEGA_BLOCKS = nbpc * 256;  // 256 CUs on MI355X

  mega_kernel<<<MEGA_BLOCKS, 256, 0, stream>>>(a);
}

// Round 7
// 1377.762 us; speedup vs baseline: 1.8577x; 1.8577x over previous
//
#include <hip/hip_runtime.h>
#include <hip/hip_fp16.h>

#define N_NODES 100000
#define N_EDGES 3200000
#define OUT_DIM 176
#define LN_EPS 1e-5f

typedef _Float16 h2 __attribute__((ext_vector_type(2)));

// Bucket sort parameters: bucket = row >> 9 (512 rows/bucket)
#define NBUCK 196
#define BP_CHUNK 4096
#define BP_BLOCKS ((N_EDGES + BP_CHUNK - 1) / BP_CHUNK)  // 782

// ---------------------------------------------------------------------------
// Device-scope grid barrier: monotonic counter, one add per block per phase.
// A block only reaches phase p+1's add after count >= nblocks*p, so
// increments are phase-ordered (no reset races).
__device__ __forceinline__ void grid_barrier(int* cnt, int phase) {
  __syncthreads();
  if (threadIdx.x == 0) {
    __threadfence();  // publish this block's writes (device scope)
    __hip_atomic_fetch_add(cnt, 1, __ATOMIC_RELEASE, __HIP_MEMORY_SCOPE_AGENT);
    const int target = (int)gridDim.x * phase;
    while (__hip_atomic_load(cnt, __ATOMIC_ACQUIRE,
                             __HIP_MEMORY_SCOPE_AGENT) < target)
      __builtin_amdgcn_s_sleep(2);
    __threadfence();  // acquire all other blocks' writes
  }
  __syncthreads();
}

// ---------------------------------------------------------------------------
// Bucket mega: precount + scan + bucket_pass in ONE kernel (2 grid barriers).
// Co-residency: 782 blocks <= 4 blocks/CU x 256 CU = 1024 guaranteed by
// __launch_bounds__(256,4) (VGPR here ~80 incl. 48 edge-cache regs).
__global__ __launch_bounds__(256, 4) void bucket_mega_kernel(
    const int* __restrict__ rows, const int* __restrict__ cols,
    const float* __restrict__ vals, int* __restrict__ gcount,
    int* __restrict__ bucket_base, int* __restrict__ bucket_cursor,
    int2* __restrict__ bucketed, int* __restrict__ bar) {
  __shared__ int cnt[NBUCK], cur[NBUCK], gbase[NBUCK];
  __shared__ int sA[256], sB[256];
  const int t = threadIdx.x;

  for (int i = t; i < NBUCK; i += 256) {
    cnt[i] = 0;
    cur[i] = 0;
  }
  __syncthreads();

  // ---- phase A: load 16 edges/thread into regs, block hist -> gcount ----
  const int e0 = blockIdx.x * BP_CHUNK;
  int r_[16], c_[16];
  float v_[16];
#pragma unroll
  for (int k = 0; k < 16; ++k) {
    const int e = e0 + t + k * 256;
    if (e < N_EDGES) {
      r_[k] = rows[e];
      c_[k] = cols[e];
      v_[k] = vals[e];
      atomicAdd(&cnt[r_[k] >> 9], 1);
    } else {
      r_[k] = -1;
    }
  }
  __syncthreads();
  for (int i = t; i < NBUCK; i += 256)
    if (cnt[i]) atomicAdd(&gcount[i], cnt[i]);

  grid_barrier(bar, 1);

  // ---- phase B: block 0 scans the 196 bucket counts ----
  if (blockIdx.x == 0) {
    int v = (t < NBUCK) ? gcount[t] : 0;
    sA[t] = v;
    __syncthreads();
    int* src = sA;
    int* dst = sB;
    for (int off = 1; off < 256; off <<= 1) {
      dst[t] = src[t] + ((t >= off) ? src[t - off] : 0);
      __syncthreads();
      int* tmp = src; src = dst; dst = tmp;
    }
    if (t < NBUCK) {
      const int excl = src[t] - v;
      bucket_base[t] = excl;
      bucket_cursor[t] = excl;
    }
    if (t == 0) bucket_base[NBUCK] = N_EDGES;
  }

  grid_barrier(bar, 2);

  // ---- phase C: claim per-bucket ranges, scatter the cached edges ----
  for (int i = t; i < NBUCK; i += 256)
    gbase[i] = cnt[i] ? atomicAdd(&bucket_cursor[i], cnt[i]) : 0;
  __syncthreads();

#pragma unroll
  for (int k = 0; k < 16; ++k) {
    if (r_[k] >= 0) {
      const int b = r_[k] >> 9;
      const int lp = atomicAdd(&cur[b], 1);
      const int meta = c_[k] | ((r_[k] & 511) << 17);
      bucketed[gbase[b] + lp] = make_int2(meta, __float_as_int(v_[k]));
    }
  }
}

// ---------------------------------------------------------------------------
// Pass C: one block per bucket -> row_ptr + exact CSR order.
__global__ __launch_bounds__(512) void csr_build_kernel(
    const int2* __restrict__ bucketed, const int* __restrict__ bucket_base,
    int* __restrict__ row_ptr, int2* __restrict__ packed) {
  __shared__ int hist[512], cur[512], sA[512], sB[512];
  const int t = threadIdx.x;
  const int blk = blockIdx.x;
  const int base = bucket_base[blk];
  const int n = bucket_base[blk + 1] - base;

  hist[t] = 0;
  __syncthreads();
  for (int i = t; i < n; i += 512) {
    const int rlow = bucketed[base + i].x >> 17;
    atomicAdd(&hist[rlow], 1);
  }
  __syncthreads();

  sA[t] = hist[t];
  __syncthreads();
  int* src = sA;
  int* dst = sB;
  for (int off = 1; off < 512; off <<= 1) {
    dst[t] = src[t] + ((t >= off) ? src[t - off] : 0);
    __syncthreads();
    int* tmp = src; src = dst; dst = tmp;
  }
  const int excl = src[t] - hist[t];

  const int row0 = blk << 9;
  if (row0 + t < N_NODES) row_ptr[row0 + t] = base + excl;
  if (blk == NBUCK - 1 && t == 0) row_ptr[N_NODES] = N_EDGES;
  cur[t] = excl;
  __syncthreads();

  for (int i = t; i < n; i += 512) {
    const int2 m = bucketed[base + i];
    const int rlow = m.x >> 17;
    const int col = m.x & 0x1FFFF;
    const int p = atomicAdd(&cur[rlow], 1);
    packed[base + p] = make_int2(col, m.y);
  }
}

// ===========================================================================
// MEGA KERNEL: convert + wprep + 3x (spmm ; dense) in ONE dispatch.
// Round-6 lesson: (256,8) forced a 64-VGPR budget -> compiler collapsed to
// 32 VGPR + scratch spill (1.66 GB of spill traffic = the whole 3.9 ms).
// (256,4) gives a 128-VGPR budget: dense's 64 resident weight regs fit
// (standalone dense compiled to exactly 64 at this bound). Grid from the
// occupancy query so co-residency (grid-barrier safety) always holds.
// ===========================================================================

struct MegaArgs {
  const float* emb;
  float* out;
  __half* emb_h;
  const float* w1r[3];
  const float* w2r[3];
  __half* wt1[3];
  __half* wt2[3];
  const float* b1[3];
  const float* b2[3];
  const float* g1[3];
  const float* be1[3];
  const float* g2[3];
  const float* be2[3];
  const int* row_ptr;
  const long long* packed;
  __half* side_h;
  __half* ego1_h;
  __half* ego2_h;
  int* bar;
};

// ---- spmm phase (v3 structure): one wave per node, grid-stride ----
template <int DIN>
__device__ void dev_spmm(const __half* ego_h, const int* row_ptr,
                         const long long* packed, __half* side_out_h,
                         int lane, int waveId, int nwaves) {
  constexpr int LPH = DIN / 8;    // lanes per edge-row (16B fp16 chunks)
  constexpr int NGRP = 64 / LPH;  // edges concurrent

  const int li = lane % LPH;
  const int grp = lane / LPH;
  const uint4* ego8 = (const uint4*)ego_h;

  for (int node = waveId; node < N_NODES; node += nwaves) {
    const int start = row_ptr[node];
    const int end = row_ptr[node + 1];

    float s[8] = {0.f, 0.f, 0.f, 0.f, 0.f, 0.f, 0.f, 0.f};

    for (int base = start; base < end; base += 64) {
      const int idx = base + lane;
      long long m = 0;  // col=0, val=0 padding contributes 0
      if (idx < end) m = __builtin_nontemporal_load(packed + idx);
      const int mc = (int)m;
      const int mv = (int)(m >> 32);
      const int cnt = min(end - base, 64);
      const int kmax = (cnt + NGRP - 1) / NGRP;
      for (int k = 0; k < kmax; ++k) {
        const int src = k * NGRP + grp;
        const int c = __shfl(mc, src, 64);
        const float v = __int_as_float(__shfl(mv, src, 64));
        uint4 raw = ego8[(long)c * LPH + li];
        const __half2* hp = (const __half2*)&raw;
        const float2 f0 = __half22float2(hp[0]);
        const float2 f1 = __half22float2(hp[1]);
        const float2 f2 = __half22float2(hp[2]);
        const float2 f3 = __half22float2(hp[3]);
        s[0] += v * f0.x; s[1] += v * f0.y;
        s[2] += v * f1.x; s[3] += v * f1.y;
        s[4] += v * f2.x; s[5] += v * f2.y;
        s[6] += v * f3.x; s[7] += v * f3.y;
      }
    }

#pragma unroll
    for (int mask = LPH; mask < 64; mask <<= 1)
#pragma unroll
      for (int r = 0; r < 8; ++r) s[r] += __shfl_xor(s[r], mask, 64);

    if (grp == 0) {
      __half2 p0 = __floats2half2_rn(s[0], s[1]);
      __half2 p1 = __floats2half2_rn(s[2], s[3]);
      __half2 p2 = __floats2half2_rn(s[4], s[5]);
      __half2 p3 = __floats2half2_rn(s[6], s[7]);
      uint4 u;
      u.x = *(unsigned int*)&p0;
      u.y = *(unsigned int*)&p1;
      u.z = *(unsigned int*)&p2;
      u.w = *(unsigned int*)&p3;
      ((uint4*)side_out_h)[(long)node * LPH + li] = u;
    }
  }
}

// ---- dense phase (v4 structure): LDS gang staging, grid-stride ----
template <int DIN, int DOUT, int COL_OFF>
__device__ void dev_dense(const __half* ego_h, const __half* side_h,
                          const __half* w1t, const float* b1,
                          const __half* w2t, const float* b2,
                          const float* g1, const float* be1,
                          const float* g2, const float* be2,
                          __half* ego_h_out, float* out,
                          uint4 (*lds)[2][64], int lane, int w, int waveId,
                          int nwaves) {
  constexpr int CH = DIN / 8;      // uint4 chunks per node row
  constexpr int G = 64 / CH;       // nodes per staged gang
  constexpr int NPW = 64 / DOUT;   // nodes per dot pass
  constexpr int PASSES = G / NPW;  // dot passes per gang

  const int j = lane % DOUT;
  const int sub = lane / DOUT;
  const int sn = lane / CH;  // node-in-gang this lane stages
  const int sc = lane % CH;  // chunk-in-node this lane stages

  const uint4* w1u = (const uint4*)w1t;
  const uint4* w2u = (const uint4*)w2t;
  uint4 wraw1[CH], wraw2[CH];
#pragma unroll
  for (int q = 0; q < CH; ++q) {
    wraw1[q] = w1u[j * CH + q];
    wraw2[q] = w2u[j * CH + q];
  }
  const float bb1 = b1[j], bb2 = b2[j];
  const float gg1 = g1[j], gg2 = g2[j];
  const float bbe1 = be1[j], bbe2 = be2[j];

  const uint4* ego8 = (const uint4*)ego_h;
  const uint4* side8 = (const uint4*)side_h;
  const int ngangs = N_NODES / G;  // exact: 100000 % {8,16} == 0

  uint4 eR, sR;
  if (waveId < ngangs) {
    const size_t b = (size_t)(waveId * G + sn) * CH + sc;
    eR = ego8[b];
    sR = side8[b];
  }

  for (int gang = waveId; gang < ngangs; gang += nwaves) {
    uint4 xsU, xpU;
    {
      const h2* e2 = (const h2*)&eR;
      const h2* s2 = (const h2*)&sR;
      h2* xs2 = (h2*)&xsU;
      h2* xp2 = (h2*)&xpU;
#pragma unroll
      for (int r = 0; r < 4; ++r) {
        xs2[r] = e2[r] + s2[r];
        xp2[r] = e2[r] * s2[r];
      }
    }
    // prior gang's ds_reads fully retired before overwriting the slab
    asm volatile("s_waitcnt lgkmcnt(0)" ::: "memory");
    __builtin_amdgcn_sched_barrier(0);
    lds[w][0][lane] = xsU;
    lds[w][1][lane] = xpU;

    // prefetch next gang into the 8 staging VGPRs (no wait)
    const int gn = gang + nwaves;
    if (gn < ngangs) {
      const size_t b = (size_t)(gn * G + sn) * CH + sc;
      eR = ego8[b];
      sR = side8[b];
    }

    // ds_writes visible to all lanes of this wave before the reads
    asm volatile("s_waitcnt lgkmcnt(0)" ::: "memory");
    __builtin_amdgcn_sched_barrier(0);

#pragma unroll
    for (int p = 0; p < PASSES; ++p) {
      const int nin = p * NPW + sub;
      const int node = gang * G + nin;

      float a1a = bb1, a1b = 0.f, a2a = bb2, a2b = 0.f;
#pragma unroll
      for (int q = 0; q < CH; ++q) {
        uint4 xsq = lds[w][0][nin * CH + q];
        uint4 xpq = lds[w][1][nin * CH + q];
        const h2* xs2 = (const h2*)&xsq;
        const h2* xp2 = (const h2*)&xpq;
        const h2* wq1 = (const h2*)&wraw1[q];
        const h2* wq2 = (const h2*)&wraw2[q];
#pragma unroll
        for (int r = 0; r < 4; ++r) {
#if __has_builtin(__builtin_amdgcn_fdot2)
          if (q & 1) {
            a1b = __builtin_amdgcn_fdot2(xs2[r], wq1[r], a1b, false);
            a2b = __builtin_amdgcn_fdot2(xp2[r], wq2[r], a2b, false);
          } else {
            a1a = __builtin_amdgcn_fdot2(xs2[r], wq1[r], a1a, false);
            a2a = __builtin_amdgcn_fdot2(xp2[r], wq2[r], a2a, false);
          }
#else
          if (q & 1) {
            a1b += (float)xs2[r].x * (float)wq1[r].x +
                   (float)xs2[r].y * (float)wq1[r].y;
            a2b += (float)xp2[r].x * (float)wq2[r].x +
                   (float)xp2[r].y * (float)wq2[r].y;
          } else {
            a1a += (float)xs2[r].x * (float)wq1[r].x +
                   (float)xs2[r].y * (float)wq1[r].y;
            a2a += (float)xp2[r].x * (float)wq2[r].x +
                   (float)xp2[r].y * (float)wq2[r].y;
          }
#endif
        }
      }

      const float acc1 = a1a + a1b;
      const float acc2 = a2a + a2b;
      const float h1 = acc1 > 0.f ? acc1 : 0.01f * acc1;
      const float h2v = acc2 > 0.f ? acc2 : 0.01f * acc2;

      float s1 = h1, q1 = h1 * h1, s2 = h2v, q2 = h2v * h2v;
#pragma unroll
      for (int mask = DOUT / 2; mask > 0; mask >>= 1) {
        s1 += __shfl_xor(s1, mask, DOUT);
        q1 += __shfl_xor(q1, mask, DOUT);
        s2 += __shfl_xor(s2, mask, DOUT);
        q2 += __shfl_xor(q2, mask, DOUT);
      }
      const float m1 = s1 * (1.0f / DOUT);
      const float m2 = s2 * (1.0f / DOUT);
      const float v1 = fmaxf(q1 * (1.0f / DOUT) - m1 * m1, 0.f);
      const float v2 = fmaxf(q2 * (1.0f / DOUT) - m2 * m2, 0.f);
      const float sv = (h1 - m1) * rsqrtf(v1 + LN_EPS) * gg1 + bbe1;
      const float bv = (h2v - m2) * rsqrtf(v2 + LN_EPS) * gg2 + bbe2;
      const float en = sv + bv;

      float ss = en * en;
#pragma unroll
      for (int mask = DOUT / 2; mask > 0; mask >>= 1) {
        ss += __shfl_xor(ss, mask, DOUT);
      }
      const float ov = en / fmaxf(sqrtf(ss), 1e-12f);

      if (ego_h_out) ego_h_out[(long)node * DOUT + j] = __float2half(en);
      out[(long)node * OUT_DIM + COL_OFF + j] = ov;
    }
  }
}

__global__ __launch_bounds__(256, 4) void mega_kernel(MegaArgs a) {
  __shared__ uint4 lds[4][2][64];  // per-wave xs/xp gang slab (8 KB)

  const int lane = threadIdx.x & 63;
  const int w = threadIdx.x >> 6;
  const int tid = blockIdx.x * 256 + threadIdx.x;
  const int nthreads = (int)gridDim.x * 256;
  const int waveId = tid >> 6;
  const int nwaves = nthreads >> 6;

  // ---- phase 0: convert emb (out[:,0:64] + emb_h) and weight prep ----
  for (int t = tid; t < N_NODES * 16; t += nthreads) {
    const int n = t >> 4, q = t & 15;
    float4 v = ((const float4*)a.emb)[t];
    ((float4*)a.out)[n * 44 + q] = v;
    __half2 ha = __floats2half2_rn(v.x, v.y);
    __half2 hb = __floats2half2_rn(v.z, v.w);
    uint2 u;
    u.x = *(unsigned int*)&ha;
    u.y = *(unsigned int*)&hb;
    ((uint2*)a.emb_h)[t] = u;
  }
  for (int i0 = tid; i0 < 4096 + 2048 + 512; i0 += nthreads) {
    int idx = i0;
    const float* w1;
    const float* w2;
    __half* t1;
    __half* t2;
    int din, dout;
    if (idx < 4096) {
      w1 = a.w1r[0]; w2 = a.w2r[0]; t1 = a.wt1[0]; t2 = a.wt2[0];
      din = 64; dout = 64;
    } else if (idx < 4096 + 2048) {
      idx -= 4096;
      w1 = a.w1r[1]; w2 = a.w2r[1]; t1 = a.wt1[1]; t2 = a.wt2[1];
      din = 64; dout = 32;
    } else {
      idx -= 4096 + 2048;
      w1 = a.w1r[2]; w2 = a.w2r[2]; t1 = a.wt1[2]; t2 = a.wt2[2];
      din = 32; dout = 16;
    }
    const int i = idx / dout, jj = idx % dout;
    t1[jj * din + i] = __float2half(w1[idx]);
    t2[jj * din + i] = __float2half(w2[idx]);
  }
  grid_barrier(a.bar, 1);

  // ---- layer 0: 64 -> 64 ----
  dev_spmm<64>(a.emb_h, a.row_ptr, a.packed, a.side_h, lane, waveId, nwaves);
  grid_barrier(a.bar, 2);
  dev_dense<64, 64, 64>(a.emb_h, a.side_h, a.wt1[0], a.b1[0], a.wt2[0],
                        a.b2[0], a.g1[0], a.be1[0], a.g2[0], a.be2[0],
                        a.ego1_h, a.out, lds, lane, w, waveId, nwaves);
  grid_barrier(a.bar, 3);

  // ---- layer 1: 64 -> 32 ----
  dev_spmm<64>(a.ego1_h, a.row_ptr, a.packed, a.side_h, lane, waveId, nwaves);
  grid_barrier(a.bar, 4);
  dev_dense<64, 32, 128>(a.ego1_h, a.side_h, a.wt1[1], a.b1[1], a.wt2[1],
                         a.b2[1], a.g1[1], a.be1[1], a.g2[1], a.be2[1],
                         a.ego2_h, a.out, lds, lane, w, waveId, nwaves);
  grid_barrier(a.bar, 5);

  // ---- layer 2: 32 -> 16 ----
  dev_spmm<32>(a.ego2_h, a.row_ptr, a.packed, a.side_h, lane, waveId, nwaves);
  grid_barrier(a.bar, 6);
  dev_dense<32, 16, 160>(a.ego2_h, a.side_h, a.wt1[2], a.b1[2], a.wt2[2],
                         a.b2[2], a.g1[2], a.be1[2], a.g2[2], a.be2[2],
                         nullptr, a.out, lds, lane, w, waveId, nwaves);
}

// ---------------------------------------------------------------------------
extern "C" void kernel_launch(void* const* d_in, const int* in_sizes, int n_in,
                              void* d_out, int out_size, void* d_ws,
                              size_t ws_size, hipStream_t stream) {
  const float* emb = (const float*)d_in[0];
  const int* rows = (const int*)d_in[1];
  const int* cols = (const int*)d_in[2];
  const float* vals = (const float*)d_in[3];

  const float* P[3][8];
  for (int k = 0; k < 3; ++k)
    for (int p = 0; p < 8; ++p) P[k][p] = (const float*)d_in[4 + 8 * k + p];

  float* out = (float*)d_out;

  char* ws = (char*)d_ws;
  int2* packed = (int2*)ws;                   // E*8   = 25.6 MB
  char* sideArea = ws + (size_t)N_EDGES * 8;  // 25.6 MB region
  __half* side_h = (__half*)sideArea;         // N*64*2 = 12.8 MB used
  int2* bucketed = (int2*)sideArea;  // ALIAS: dead before spmm writes side
  __half* emb_h = (__half*)(sideArea + (size_t)N_NODES * 64 * 4);  // 12.8 MB
  __half* ego1_h = emb_h + (size_t)N_NODES * 64;                   // 12.8 MB
  __half* ego2_h = ego1_h + (size_t)N_NODES * 64;                  // 6.4 MB
  // transposed fp16 weights (16B-aligned block)
  __half* wt1_0 = ego2_h + (size_t)N_NODES * 32;  // 4096 halves
  __half* wt2_0 = wt1_0 + 4096;
  __half* wt1_1 = wt2_0 + 4096;  // 2048
  __half* wt2_1 = wt1_1 + 2048;
  __half* wt1_2 = wt2_1 + 2048;  // 512
  __half* wt2_2 = wt1_2 + 512;
  int* row_ptr = (int*)(wt2_2 + 512);  // N+1
  int* gcount = row_ptr + (N_NODES + 1);
  int* bar0 = gcount + NBUCK;      // bucket_mega barrier counter
  int* bar = bar0 + 1;             // mega barrier counter
  int* bucket_base = bar + 1;
  int* bucket_cursor = bucket_base + (NBUCK + 1);

  // ---- CSR build: memset + bucket_mega + csr_build (2 kernels) ----
  hipMemsetAsync(gcount, 0, (NBUCK + 2) * sizeof(int), stream);  // + bars
  bucket_mega_kernel<<<BP_BLOCKS, 256, 0, stream>>>(
      rows, cols, vals, gcount, bucket_base, bucket_cursor, bucketed, bar0);
  csr_build_kernel<<<NBUCK, 512, 0, stream>>>(bucketed, bucket_base, row_ptr,
                                              packed);

  // ---- mega kernel: convert + wprep + 3x (spmm ; dense) ----
  MegaArgs a;
  a.emb = emb;
  a.out = out;
  a.emb_h = emb_h;
  a.w1r[0] = P[0][0]; a.w2r[0] = P[0][2];
  a.w1r[1] = P[1][0]; a.w2r[1] = P[1][2];
  a.w1r[2] = P[2][0]; a.w2r[2] = P[2][2];
  a.wt1[0] = wt1_0; a.wt2[0] = wt2_0;
  a.wt1[1] = wt1_1; a.wt2[1] = wt2_1;
  a.wt1[2] = wt1_2; a.wt2[2] = wt2_2;
  for (int k = 0; k < 3; ++k) {
    a.b1[k] = P[k][1];
    a.b2[k] = P[k][3];
    a.g1[k] = P[k][4];
    a.be1[k] = P[k][5];
    a.g2[k] = P[k][6];
    a.be2[k] = P[k][7];
  }
  a.row_ptr = row_ptr;
  a.packed = (const long long*)packed;
  a.side_h = side_h;
  a.ego1_h = ego1_h;
  a.ego2_h = ego2_h;
  a.bar = bar;

  // Grid sized for guaranteed co-residency (software grid barrier safety).
  int nbpc = 0;
  if (hipOccupancyMaxActiveBlocksPerMultiprocessor(&nbpc, mega_kernel, 256,
                                                   0) != hipSuccess ||
      nbpc < 1)
    nbpc = 4;  // (256,4) guarantees >=4 blocks/CU
  if (nbpc > 8) nbpc = 8;
  const int MEGA_BLOCKS = nbpc * 256;  // 256 CUs on MI355X

  mega_kernel<<<MEGA_BLOCKS, 256, 0, stream>>>(a);
}

// Round 8
// 1064.014 us; speedup vs baseline: 2.4055x; 1.2949x over previous
//
#include <hip/hip_runtime.h>
#include <hip/hip_fp16.h>

#define N_NODES 100000
#define N_EDGES 3200000
#define OUT_DIM 176
#define LN_EPS 1e-5f

typedef _Float16 h2 __attribute__((ext_vector_type(2)));

// Bucket sort parameters: bucket = row >> 9 (512 rows/bucket)
#define NBUCK 196
#define BP_CHUNK 4096
#define BP_BLOCKS ((N_EDGES + BP_CHUNK - 1) / BP_CHUNK)  // 782

// ---------------------------------------------------------------------------
// Device-scope grid barrier, v2.
// Round-7 lesson: ACQUIRE-per-poll-iteration invalidates the XCD's L2 every
// spin (gfx950 agent-scope acquire = L2 inv, since per-XCD L2s are not
// coherent). 2048 spinners continuously nuked every XCD's L2 while stragglers
// worked -> all L2 hits became L3 hits -> 4x kernel slowdown at identical
// HBM bytes. v2: release RMW on arrival (one L2 writeback), RELAXED polling
// (no cache side effects), s_sleep backoff, ONE acquire load at exit (one
// L2 invalidate per block per phase).
__device__ __forceinline__ void grid_barrier(int* cnt, int phase) {
  __syncthreads();
  if (threadIdx.x == 0) {
    __hip_atomic_fetch_add(cnt, 1, __ATOMIC_RELEASE, __HIP_MEMORY_SCOPE_AGENT);
    const int target = (int)gridDim.x * phase;
    while (__hip_atomic_load(cnt, __ATOMIC_RELAXED,
                             __HIP_MEMORY_SCOPE_AGENT) < target)
      __builtin_amdgcn_s_sleep(64);
    // single acquire: invalidate stale L1/L2 once, now that all writes landed
    (void)__hip_atomic_load(cnt, __ATOMIC_ACQUIRE, __HIP_MEMORY_SCOPE_AGENT);
  }
  __syncthreads();
}

// ---------------------------------------------------------------------------
// Bucket mega: precount + scan + bucket_pass in ONE kernel (2 grid barriers).
// Co-residency: 782 blocks <= 4 blocks/CU x 256 CU = 1024 guaranteed by
// __launch_bounds__(256,4).
__global__ __launch_bounds__(256, 4) void bucket_mega_kernel(
    const int* __restrict__ rows, const int* __restrict__ cols,
    const float* __restrict__ vals, int* __restrict__ gcount,
    int* __restrict__ bucket_base, int* __restrict__ bucket_cursor,
    int2* __restrict__ bucketed, int* __restrict__ bar) {
  __shared__ int cnt[NBUCK], cur[NBUCK], gbase[NBUCK];
  __shared__ int sA[256], sB[256];
  const int t = threadIdx.x;

  for (int i = t; i < NBUCK; i += 256) {
    cnt[i] = 0;
    cur[i] = 0;
  }
  __syncthreads();

  // ---- phase A: load 16 edges/thread into regs, block hist -> gcount ----
  const int e0 = blockIdx.x * BP_CHUNK;
  int r_[16], c_[16];
  float v_[16];
#pragma unroll
  for (int k = 0; k < 16; ++k) {
    const int e = e0 + t + k * 256;
    if (e < N_EDGES) {
      r_[k] = rows[e];
      c_[k] = cols[e];
      v_[k] = vals[e];
      atomicAdd(&cnt[r_[k] >> 9], 1);
    } else {
      r_[k] = -1;
    }
  }
  __syncthreads();
  for (int i = t; i < NBUCK; i += 256)
    if (cnt[i]) atomicAdd(&gcount[i], cnt[i]);

  grid_barrier(bar, 1);

  // ---- phase B: block 0 scans the 196 bucket counts ----
  if (blockIdx.x == 0) {
    int v = (t < NBUCK) ? gcount[t] : 0;
    sA[t] = v;
    __syncthreads();
    int* src = sA;
    int* dst = sB;
    for (int off = 1; off < 256; off <<= 1) {
      dst[t] = src[t] + ((t >= off) ? src[t - off] : 0);
      __syncthreads();
      int* tmp = src; src = dst; dst = tmp;
    }
    if (t < NBUCK) {
      const int excl = src[t] - v;
      bucket_base[t] = excl;
      bucket_cursor[t] = excl;
    }
    if (t == 0) bucket_base[NBUCK] = N_EDGES;
  }

  grid_barrier(bar, 2);

  // ---- phase C: claim per-bucket ranges, scatter the cached edges ----
  for (int i = t; i < NBUCK; i += 256)
    gbase[i] = cnt[i] ? atomicAdd(&bucket_cursor[i], cnt[i]) : 0;
  __syncthreads();

#pragma unroll
  for (int k = 0; k < 16; ++k) {
    if (r_[k] >= 0) {
      const int b = r_[k] >> 9;
      const int lp = atomicAdd(&cur[b], 1);
      const int meta = c_[k] | ((r_[k] & 511) << 17);
      bucketed[gbase[b] + lp] = make_int2(meta, __float_as_int(v_[k]));
    }
  }
}

// ---------------------------------------------------------------------------
// Pass C: one block per bucket -> row_ptr + exact CSR order.
__global__ __launch_bounds__(512) void csr_build_kernel(
    const int2* __restrict__ bucketed, const int* __restrict__ bucket_base,
    int* __restrict__ row_ptr, int2* __restrict__ packed) {
  __shared__ int hist[512], cur[512], sA[512], sB[512];
  const int t = threadIdx.x;
  const int blk = blockIdx.x;
  const int base = bucket_base[blk];
  const int n = bucket_base[blk + 1] - base;

  hist[t] = 0;
  __syncthreads();
  for (int i = t; i < n; i += 512) {
    const int rlow = bucketed[base + i].x >> 17;
    atomicAdd(&hist[rlow], 1);
  }
  __syncthreads();

  sA[t] = hist[t];
  __syncthreads();
  int* src = sA;
  int* dst = sB;
  for (int off = 1; off < 512; off <<= 1) {
    dst[t] = src[t] + ((t >= off) ? src[t - off] : 0);
    __syncthreads();
    int* tmp = src; src = dst; dst = tmp;
  }
  const int excl = src[t] - hist[t];

  const int row0 = blk << 9;
  if (row0 + t < N_NODES) row_ptr[row0 + t] = base + excl;
  if (blk == NBUCK - 1 && t == 0) row_ptr[N_NODES] = N_EDGES;
  cur[t] = excl;
  __syncthreads();

  for (int i = t; i < n; i += 512) {
    const int2 m = bucketed[base + i];
    const int rlow = m.x >> 17;
    const int col = m.x & 0x1FFFF;
    const int p = atomicAdd(&cur[rlow], 1);
    packed[base + p] = make_int2(col, m.y);
  }
}

// ===========================================================================
// MEGA KERNEL: convert + wprep + 3x (spmm ; dense) in ONE dispatch.
// (256,4) = 128-VGPR budget (round-6's (256,8) forced spill); compiled to
// 64 VGPR in round 7 with no spill (FETCH/WRITE matched ideal). Barrier v2
// above removes the acquire-storm that made round 7 4x slow.
// ===========================================================================

struct MegaArgs {
  const float* emb;
  float* out;
  __half* emb_h;
  const float* w1r[3];
  const float* w2r[3];
  __half* wt1[3];
  __half* wt2[3];
  const float* b1[3];
  const float* b2[3];
  const float* g1[3];
  const float* be1[3];
  const float* g2[3];
  const float* be2[3];
  const int* row_ptr;
  const long long* packed;
  __half* side_h;
  __half* ego1_h;
  __half* ego2_h;
  int* bar;
};

// ---- spmm phase (v3 structure): one wave per node, grid-stride ----
template <int DIN>
__device__ void dev_spmm(const __half* ego_h, const int* row_ptr,
                         const long long* packed, __half* side_out_h,
                         int lane, int waveId, int nwaves) {
  constexpr int LPH = DIN / 8;    // lanes per edge-row (16B fp16 chunks)
  constexpr int NGRP = 64 / LPH;  // edges concurrent

  const int li = lane % LPH;
  const int grp = lane / LPH;
  const uint4* ego8 = (const uint4*)ego_h;

  for (int node = waveId; node < N_NODES; node += nwaves) {
    const int start = row_ptr[node];
    const int end = row_ptr[node + 1];

    float s[8] = {0.f, 0.f, 0.f, 0.f, 0.f, 0.f, 0.f, 0.f};

    for (int base = start; base < end; base += 64) {
      const int idx = base + lane;
      long long m = 0;  // col=0, val=0 padding contributes 0
      if (idx < end) m = __builtin_nontemporal_load(packed + idx);
      const int mc = (int)m;
      const int mv = (int)(m >> 32);
      const int cnt = min(end - base, 64);
      const int kmax = (cnt + NGRP - 1) / NGRP;
      for (int k = 0; k < kmax; ++k) {
        const int src = k * NGRP + grp;
        const int c = __shfl(mc, src, 64);
        const float v = __int_as_float(__shfl(mv, src, 64));
        uint4 raw = ego8[(long)c * LPH + li];
        const __half2* hp = (const __half2*)&raw;
        const float2 f0 = __half22float2(hp[0]);
        const float2 f1 = __half22float2(hp[1]);
        const float2 f2 = __half22float2(hp[2]);
        const float2 f3 = __half22float2(hp[3]);
        s[0] += v * f0.x; s[1] += v * f0.y;
        s[2] += v * f1.x; s[3] += v * f1.y;
        s[4] += v * f2.x; s[5] += v * f2.y;
        s[6] += v * f3.x; s[7] += v * f3.y;
      }
    }

#pragma unroll
    for (int mask = LPH; mask < 64; mask <<= 1)
#pragma unroll
      for (int r = 0; r < 8; ++r) s[r] += __shfl_xor(s[r], mask, 64);

    if (grp == 0) {
      __half2 p0 = __floats2half2_rn(s[0], s[1]);
      __half2 p1 = __floats2half2_rn(s[2], s[3]);
      __half2 p2 = __floats2half2_rn(s[4], s[5]);
      __half2 p3 = __floats2half2_rn(s[6], s[7]);
      uint4 u;
      u.x = *(unsigned int*)&p0;
      u.y = *(unsigned int*)&p1;
      u.z = *(unsigned int*)&p2;
      u.w = *(unsigned int*)&p3;
      ((uint4*)side_out_h)[(long)node * LPH + li] = u;
    }
  }
}

// ---- dense phase (v4 structure): LDS gang staging, grid-stride ----
template <int DIN, int DOUT, int COL_OFF>
__device__ void dev_dense(const __half* ego_h, const __half* side_h,
                          const __half* w1t, const float* b1,
                          const __half* w2t, const float* b2,
                          const float* g1, const float* be1,
                          const float* g2, const float* be2,
                          __half* ego_h_out, float* out,
                          uint4 (*lds)[2][64], int lane, int w, int waveId,
                          int nwaves) {
  constexpr int CH = DIN / 8;      // uint4 chunks per node row
  constexpr int G = 64 / CH;       // nodes per staged gang
  constexpr int NPW = 64 / DOUT;   // nodes per dot pass
  constexpr int PASSES = G / NPW;  // dot passes per gang

  const int j = lane % DOUT;
  const int sub = lane / DOUT;
  const int sn = lane / CH;  // node-in-gang this lane stages
  const int sc = lane % CH;  // chunk-in-node this lane stages

  const uint4* w1u = (const uint4*)w1t;
  const uint4* w2u = (const uint4*)w2t;
  uint4 wraw1[CH], wraw2[CH];
#pragma unroll
  for (int q = 0; q < CH; ++q) {
    wraw1[q] = w1u[j * CH + q];
    wraw2[q] = w2u[j * CH + q];
  }
  const float bb1 = b1[j], bb2 = b2[j];
  const float gg1 = g1[j], gg2 = g2[j];
  const float bbe1 = be1[j], bbe2 = be2[j];

  const uint4* ego8 = (const uint4*)ego_h;
  const uint4* side8 = (const uint4*)side_h;
  const int ngangs = N_NODES / G;  // exact: 100000 % {8,16} == 0

  uint4 eR, sR;
  if (waveId < ngangs) {
    const size_t b = (size_t)(waveId * G + sn) * CH + sc;
    eR = ego8[b];
    sR = side8[b];
  }

  for (int gang = waveId; gang < ngangs; gang += nwaves) {
    uint4 xsU, xpU;
    {
      const h2* e2 = (const h2*)&eR;
      const h2* s2 = (const h2*)&sR;
      h2* xs2 = (h2*)&xsU;
      h2* xp2 = (h2*)&xpU;
#pragma unroll
      for (int r = 0; r < 4; ++r) {
        xs2[r] = e2[r] + s2[r];
        xp2[r] = e2[r] * s2[r];
      }
    }
    // prior gang's ds_reads fully retired before overwriting the slab
    asm volatile("s_waitcnt lgkmcnt(0)" ::: "memory");
    __builtin_amdgcn_sched_barrier(0);
    lds[w][0][lane] = xsU;
    lds[w][1][lane] = xpU;

    // prefetch next gang into the 8 staging VGPRs (no wait)
    const int gn = gang + nwaves;
    if (gn < ngangs) {
      const size_t b = (size_t)(gn * G + sn) * CH + sc;
      eR = ego8[b];
      sR = side8[b];
    }

    // ds_writes visible to all lanes of this wave before the reads
    asm volatile("s_waitcnt lgkmcnt(0)" ::: "memory");
    __builtin_amdgcn_sched_barrier(0);

#pragma unroll
    for (int p = 0; p < PASSES; ++p) {
      const int nin = p * NPW + sub;
      const int node = gang * G + nin;

      float a1a = bb1, a1b = 0.f, a2a = bb2, a2b = 0.f;
#pragma unroll
      for (int q = 0; q < CH; ++q) {
        uint4 xsq = lds[w][0][nin * CH + q];
        uint4 xpq = lds[w][1][nin * CH + q];
        const h2* xs2 = (const h2*)&xsq;
        const h2* xp2 = (const h2*)&xpq;
        const h2* wq1 = (const h2*)&wraw1[q];
        const h2* wq2 = (const h2*)&wraw2[q];
#pragma unroll
        for (int r = 0; r < 4; ++r) {
#if __has_builtin(__builtin_amdgcn_fdot2)
          if (q & 1) {
            a1b = __builtin_amdgcn_fdot2(xs2[r], wq1[r], a1b, false);
            a2b = __builtin_amdgcn_fdot2(xp2[r], wq2[r], a2b, false);
          } else {
            a1a = __builtin_amdgcn_fdot2(xs2[r], wq1[r], a1a, false);
            a2a = __builtin_amdgcn_fdot2(xp2[r], wq2[r], a2a, false);
          }
#else
          if (q & 1) {
            a1b += (float)xs2[r].x * (float)wq1[r].x +
                   (float)xs2[r].y * (float)wq1[r].y;
            a2b += (float)xp2[r].x * (float)wq2[r].x +
                   (float)xp2[r].y * (float)wq2[r].y;
          } else {
            a1a += (float)xs2[r].x * (float)wq1[r].x +
                   (float)xs2[r].y * (float)wq1[r].y;
            a2a += (float)xp2[r].x * (float)wq2[r].x +
                   (float)xp2[r].y * (float)wq2[r].y;
          }
#endif
        }
      }

      const float acc1 = a1a + a1b;
      const float acc2 = a2a + a2b;
      const float h1 = acc1 > 0.f ? acc1 : 0.01f * acc1;
      const float h2v = acc2 > 0.f ? acc2 : 0.01f * acc2;

      float s1 = h1, q1 = h1 * h1, s2 = h2v, q2 = h2v * h2v;
#pragma unroll
      for (int mask = DOUT / 2; mask > 0; mask >>= 1) {
        s1 += __shfl_xor(s1, mask, DOUT);
        q1 += __shfl_xor(q1, mask, DOUT);
        s2 += __shfl_xor(s2, mask, DOUT);
        q2 += __shfl_xor(q2, mask, DOUT);
      }
      const float m1 = s1 * (1.0f / DOUT);
      const float m2 = s2 * (1.0f / DOUT);
      const float v1 = fmaxf(q1 * (1.0f / DOUT) - m1 * m1, 0.f);
      const float v2 = fmaxf(q2 * (1.0f / DOUT) - m2 * m2, 0.f);
      const float sv = (h1 - m1) * rsqrtf(v1 + LN_EPS) * gg1 + bbe1;
      const float bv = (h2v - m2) * rsqrtf(v2 + LN_EPS) * gg2 + bbe2;
      const float en = sv + bv;

      float ss = en * en;
#pragma unroll
      for (int mask = DOUT / 2; mask > 0; mask >>= 1) {
        ss += __shfl_xor(ss, mask, DOUT);
      }
      const float ov = en / fmaxf(sqrtf(ss), 1e-12f);

      if (ego_h_out) ego_h_out[(long)node * DOUT + j] = __float2half(en);
      out[(long)node * OUT_DIM + COL_OFF + j] = ov;
    }
  }
}

__global__ __launch_bounds__(256, 4) void mega_kernel(MegaArgs a) {
  __shared__ uint4 lds[4][2][64];  // per-wave xs/xp gang slab (8 KB)

  const int lane = threadIdx.x & 63;
  const int w = threadIdx.x >> 6;
  const int tid = blockIdx.x * 256 + threadIdx.x;
  const int nthreads = (int)gridDim.x * 256;
  const int waveId = tid >> 6;
  const int nwaves = nthreads >> 6;

  // ---- phase 0: convert emb (out[:,0:64] + emb_h) and weight prep ----
  for (int t = tid; t < N_NODES * 16; t += nthreads) {
    const int n = t >> 4, q = t & 15;
    float4 v = ((const float4*)a.emb)[t];
    ((float4*)a.out)[n * 44 + q] = v;
    __half2 ha = __floats2half2_rn(v.x, v.y);
    __half2 hb = __floats2half2_rn(v.z, v.w);
    uint2 u;
    u.x = *(unsigned int*)&ha;
    u.y = *(unsigned int*)&hb;
    ((uint2*)a.emb_h)[t] = u;
  }
  for (int i0 = tid; i0 < 4096 + 2048 + 512; i0 += nthreads) {
    int idx = i0;
    const float* w1;
    const float* w2;
    __half* t1;
    __half* t2;
    int din, dout;
    if (idx < 4096) {
      w1 = a.w1r[0]; w2 = a.w2r[0]; t1 = a.wt1[0]; t2 = a.wt2[0];
      din = 64; dout = 64;
    } else if (idx < 4096 + 2048) {
      idx -= 4096;
      w1 = a.w1r[1]; w2 = a.w2r[1]; t1 = a.wt1[1]; t2 = a.wt2[1];
      din = 64; dout = 32;
    } else {
      idx -= 4096 + 2048;
      w1 = a.w1r[2]; w2 = a.w2r[2]; t1 = a.wt1[2]; t2 = a.wt2[2];
      din = 32; dout = 16;
    }
    const int i = idx / dout, jj = idx % dout;
    t1[jj * din + i] = __float2half(w1[idx]);
    t2[jj * din + i] = __float2half(w2[idx]);
  }
  grid_barrier(a.bar, 1);

  // ---- layer 0: 64 -> 64 ----
  dev_spmm<64>(a.emb_h, a.row_ptr, a.packed, a.side_h, lane, waveId, nwaves);
  grid_barrier(a.bar, 2);
  dev_dense<64, 64, 64>(a.emb_h, a.side_h, a.wt1[0], a.b1[0], a.wt2[0],
                        a.b2[0], a.g1[0], a.be1[0], a.g2[0], a.be2[0],
                        a.ego1_h, a.out, lds, lane, w, waveId, nwaves);
  grid_barrier(a.bar, 3);

  // ---- layer 1: 64 -> 32 ----
  dev_spmm<64>(a.ego1_h, a.row_ptr, a.packed, a.side_h, lane, waveId, nwaves);
  grid_barrier(a.bar, 4);
  dev_dense<64, 32, 128>(a.ego1_h, a.side_h, a.wt1[1], a.b1[1], a.wt2[1],
                         a.b2[1], a.g1[1], a.be1[1], a.g2[1], a.be2[1],
                         a.ego2_h, a.out, lds, lane, w, waveId, nwaves);
  grid_barrier(a.bar, 5);

  // ---- layer 2: 32 -> 16 ----
  dev_spmm<32>(a.ego2_h, a.row_ptr, a.packed, a.side_h, lane, waveId, nwaves);
  grid_barrier(a.bar, 6);
  dev_dense<32, 16, 160>(a.ego2_h, a.side_h, a.wt1[2], a.b1[2], a.wt2[2],
                         a.b2[2], a.g1[2], a.be1[2], a.g2[2], a.be2[2],
                         nullptr, a.out, lds, lane, w, waveId, nwaves);
}

// ---------------------------------------------------------------------------
extern "C" void kernel_launch(void* const* d_in, const int* in_sizes, int n_in,
                              void* d_out, int out_size, void* d_ws,
                              size_t ws_size, hipStream_t stream) {
  const float* emb = (const float*)d_in[0];
  const int* rows = (const int*)d_in[1];
  const int* cols = (const int*)d_in[2];
  const float* vals = (const float*)d_in[3];

  const float* P[3][8];
  for (int k = 0; k < 3; ++k)
    for (int p = 0; p < 8; ++p) P[k][p] = (const float*)d_in[4 + 8 * k + p];

  float* out = (float*)d_out;

  char* ws = (char*)d_ws;
  int2* packed = (int2*)ws;                   // E*8   = 25.6 MB
  char* sideArea = ws + (size_t)N_EDGES * 8;  // 25.6 MB region
  __half* side_h = (__half*)sideArea;         // N*64*2 = 12.8 MB used
  int2* bucketed = (int2*)sideArea;  // ALIAS: dead before spmm writes side
  __half* emb_h = (__half*)(sideArea + (size_t)N_NODES * 64 * 4);  // 12.8 MB
  __half* ego1_h = emb_h + (size_t)N_NODES * 64;                   // 12.8 MB
  __half* ego2_h = ego1_h + (size_t)N_NODES * 64;                  // 6.4 MB
  // transposed fp16 weights (16B-aligned block)
  __half* wt1_0 = ego2_h + (size_t)N_NODES * 32;  // 4096 halves
  __half* wt2_0 = wt1_0 + 4096;
  __half* wt1_1 = wt2_0 + 4096;  // 2048
  __half* wt2_1 = wt1_1 + 2048;
  __half* wt1_2 = wt2_1 + 2048;  // 512
  __half* wt2_2 = wt1_2 + 512;
  int* row_ptr = (int*)(wt2_2 + 512);  // N+1
  int* gcount = row_ptr + (N_NODES + 1);
  int* bar0 = gcount + NBUCK;      // bucket_mega barrier counter
  int* bar = bar0 + 1;             // mega barrier counter
  int* bucket_base = bar + 1;
  int* bucket_cursor = bucket_base + (NBUCK + 1);

  // ---- CSR build: memset + bucket_mega + csr_build (2 kernels) ----
  hipMemsetAsync(gcount, 0, (NBUCK + 2) * sizeof(int), stream);  // + bars
  bucket_mega_kernel<<<BP_BLOCKS, 256, 0, stream>>>(
      rows, cols, vals, gcount, bucket_base, bucket_cursor, bucketed, bar0);
  csr_build_kernel<<<NBUCK, 512, 0, stream>>>(bucketed, bucket_base, row_ptr,
                                              packed);

  // ---- mega kernel: convert + wprep + 3x (spmm ; dense) ----
  MegaArgs a;
  a.emb = emb;
  a.out = out;
  a.emb_h = emb_h;
  a.w1r[0] = P[0][0]; a.w2r[0] = P[0][2];
  a.w1r[1] = P[1][0]; a.w2r[1] = P[1][2];
  a.w1r[2] = P[2][0]; a.w2r[2] = P[2][2];
  a.wt1[0] = wt1_0; a.wt2[0] = wt2_0;
  a.wt1[1] = wt1_1; a.wt2[1] = wt2_1;
  a.wt1[2] = wt1_2; a.wt2[2] = wt2_2;
  for (int k = 0; k < 3; ++k) {
    a.b1[k] = P[k][1];
    a.b2[k] = P[k][3];
    a.g1[k] = P[k][4];
    a.be1[k] = P[k][5];
    a.g2[k] = P[k][6];
    a.be2[k] = P[k][7];
  }
  a.row_ptr = row_ptr;
  a.packed = (const long long*)packed;
  a.side_h = side_h;
  a.ego1_h = ego1_h;
  a.ego2_h = ego2_h;
  a.bar = bar;

  // Grid sized for guaranteed co-residency (software grid barrier safety).
  int nbpc = 0;
  if (hipOccupancyMaxActiveBlocksPerMultiprocessor(&nbpc, mega_kernel, 256,
                                                   0) != hipSuccess ||
      nbpc < 1)
    nbpc = 4;  // (256,4) guarantees >=4 blocks/CU
  if (nbpc > 8) nbpc = 8;
  const int MEGA_BLOCKS = nbpc * 256;  // 256 CUs on MI355X

  mega_kernel<<<MEGA_BLOCKS, 256, 0, stream>>>(a);
}

// Round 9
// 498.011 us; speedup vs baseline: 5.1394x; 2.1365x over previous
//
#include <hip/hip_runtime.h>
#include <hip/hip_fp16.h>

#define N_NODES 100000
#define N_EDGES 3200000
#define OUT_DIM 176
#define LN_EPS 1e-5f

typedef _Float16 h2 __attribute__((ext_vector_type(2)));

// Bucket sort parameters: bucket = row >> 9 (512 rows/bucket)
#define NBUCK 196
#define PADCAP 17152  // static per-bucket capacity: mean 16384 + 6 sigma
#define PC_BLOCKS 512
#define PC_CHUNK (N_EDGES / PC_BLOCKS)  // 6250
#define BP_CHUNK 4096
#define BP_BLOCKS ((N_EDGES + BP_CHUNK - 1) / BP_CHUNK)  // 782

// ---------------------------------------------------------------------------
// Merged prep: out[:,0:64]=emb, emb_h=fp16(emb), AND transposed fp16 weights.
// Grid 6250 blocks; weight work rides on the first 26 blocks' threads.
__global__ __launch_bounds__(256) void prep_kernel(
    const float* __restrict__ emb, float* __restrict__ out,
    __half* __restrict__ emb_h, const float* __restrict__ w1_0,
    const float* __restrict__ w2_0, const float* __restrict__ w1_1,
    const float* __restrict__ w2_1, const float* __restrict__ w1_2,
    const float* __restrict__ w2_2, __half* __restrict__ wt1_0,
    __half* __restrict__ wt2_0, __half* __restrict__ wt1_1,
    __half* __restrict__ wt2_1, __half* __restrict__ wt1_2,
    __half* __restrict__ wt2_2) {
  const int t = blockIdx.x * 256 + threadIdx.x;
  if (t < N_NODES * 16) {
    const int n = t >> 4, q = t & 15;
    float4 v = ((const float4*)emb)[t];
    ((float4*)out)[n * 44 + q] = v;
    __half2 a = __floats2half2_rn(v.x, v.y);
    __half2 b = __floats2half2_rn(v.z, v.w);
    uint2 u;
    u.x = *(unsigned int*)&a;
    u.y = *(unsigned int*)&b;
    ((uint2*)emb_h)[t] = u;
  }
  if (t < 4096 + 2048 + 512) {
    int idx = t;
    const float* w1;
    const float* w2;
    __half* t1;
    __half* t2;
    int din, dout;
    if (idx < 4096) {
      w1 = w1_0; w2 = w2_0; t1 = wt1_0; t2 = wt2_0; din = 64; dout = 64;
    } else if (idx < 4096 + 2048) {
      idx -= 4096;
      w1 = w1_1; w2 = w2_1; t1 = wt1_1; t2 = wt2_1; din = 64; dout = 32;
    } else {
      idx -= 4096 + 2048;
      w1 = w1_2; w2 = w2_2; t1 = wt1_2; t2 = wt2_2; din = 32; dout = 16;
    }
    const int i = idx / dout, j = idx % dout;
    t1[j * din + i] = __float2half(w1[idx]);
    t2[j * din + i] = __float2half(w2[idx]);
  }
}

// ---------------------------------------------------------------------------
// Fallback path only (ws too small for padded layout): per-bucket counts.
__global__ __launch_bounds__(256) void precount_kernel(
    const int* __restrict__ rows, int* __restrict__ gcount) {
  __shared__ int hist[NBUCK];
  for (int i = threadIdx.x; i < NBUCK; i += 256) hist[i] = 0;
  __syncthreads();
  const int e0 = blockIdx.x * PC_CHUNK;
  for (int e = e0 + threadIdx.x; e < e0 + PC_CHUNK; e += 256) {
    const int r = __builtin_nontemporal_load(rows + e);
    atomicAdd(&hist[r >> 9], 1);
  }
  __syncthreads();
  for (int i = threadIdx.x; i < NBUCK; i += 256)
    if (hist[i]) atomicAdd(&gcount[i], hist[i]);
}

// Fallback path only: exclusive scan of bucket counts -> bucket_base.
__global__ __launch_bounds__(256) void bucket_scan_kernel(
    const int* __restrict__ gcount, int* __restrict__ bucket_base) {
  __shared__ int sA[256], sB[256];
  const int t = threadIdx.x;
  int v = (t < NBUCK) ? gcount[t] : 0;
  sA[t] = v;
  __syncthreads();
  int* src = sA;
  int* dst = sB;
  for (int off = 1; off < 256; off <<= 1) {
    dst[t] = src[t] + ((t >= off) ? src[t - off] : 0);
    __syncthreads();
    int* tmp = src; src = dst; dst = tmp;
  }
  if (t < NBUCK) bucket_base[t] = src[t] - v;
}

// ---------------------------------------------------------------------------
// Bucket the edges. pad_mode=1: static base b*PADCAP (no precount/scan
// needed); pad_mode=0: base from bucket_base[]. cursor[] starts at 0 in
// both modes and ends holding the per-bucket edge count.
__global__ __launch_bounds__(256) void bucket_pass_kernel(
    const int* __restrict__ rows, const int* __restrict__ cols,
    const float* __restrict__ vals, const int* __restrict__ bucket_base,
    int* __restrict__ cursor, int2* __restrict__ bucketed, int pad_mode) {
  __shared__ int cnt[NBUCK], cur[NBUCK], gbase[NBUCK];
  for (int i = threadIdx.x; i < NBUCK; i += 256) {
    cnt[i] = 0;
    cur[i] = 0;
  }
  __syncthreads();

  const int e0 = blockIdx.x * BP_CHUNK;
  int r_[16], c_[16];
  float v_[16];
#pragma unroll
  for (int k = 0; k < 16; ++k) {
    const int e = e0 + threadIdx.x + k * 256;
    if (e < N_EDGES) {
      r_[k] = rows[e];
      c_[k] = cols[e];
      v_[k] = vals[e];
      atomicAdd(&cnt[r_[k] >> 9], 1);
    } else {
      r_[k] = -1;
    }
  }
  __syncthreads();

  for (int i = threadIdx.x; i < NBUCK; i += 256) {
    if (cnt[i]) {
      const int base = pad_mode ? i * PADCAP : bucket_base[i];
      gbase[i] = base + atomicAdd(&cursor[i], cnt[i]);
    } else {
      gbase[i] = 0;
    }
  }
  __syncthreads();

#pragma unroll
  for (int k = 0; k < 16; ++k) {
    if (r_[k] >= 0) {
      const int b = r_[k] >> 9;
      const int lp = atomicAdd(&cur[b], 1);
      const int meta = c_[k] | ((r_[k] & 511) << 17);
      bucketed[gbase[b] + lp] = make_int2(meta, __float_as_int(v_[k]));
    }
  }
}

// ---------------------------------------------------------------------------
// One block per bucket -> row_ptr2 {start,end} + exact CSR order. Pads in
// the padded layout are never read (row_ptr2 carries explicit ends).
__global__ __launch_bounds__(512) void csr_build_kernel(
    const int2* __restrict__ bucketed, const int* __restrict__ bucket_base,
    const int* __restrict__ cursor, int2* __restrict__ row_ptr2,
    int2* __restrict__ packed, int pad_mode) {
  __shared__ int hist[512], cur[512], sA[512], sB[512];
  const int t = threadIdx.x;
  const int blk = blockIdx.x;
  const int base = pad_mode ? blk * PADCAP : bucket_base[blk];
  const int n = cursor[blk];

  hist[t] = 0;
  __syncthreads();
  for (int i = t; i < n; i += 512) {
    const int rlow = bucketed[base + i].x >> 17;
    atomicAdd(&hist[rlow], 1);
  }
  __syncthreads();

  sA[t] = hist[t];
  __syncthreads();
  int* src = sA;
  int* dst = sB;
  for (int off = 1; off < 512; off <<= 1) {
    dst[t] = src[t] + ((t >= off) ? src[t - off] : 0);
    __syncthreads();
    int* tmp = src; src = dst; dst = tmp;
  }
  const int excl = src[t] - hist[t];

  const int row0 = blk << 9;
  if (row0 + t < N_NODES)
    row_ptr2[row0 + t] = make_int2(base + excl, base + excl + hist[t]);
  cur[t] = excl;
  __syncthreads();

  for (int i = t; i < n; i += 512) {
    const int2 m = bucketed[base + i];
    const int rlow = m.x >> 17;
    const int col = m.x & 0x1FFFF;
    const int p = atomicAdd(&cur[rlow], 1);
    packed[base + p] = make_int2(col, m.y);
  }
}

// ---------------------------------------------------------------------------
// Gather SpMM, fp16 ego table — NO LDS. One wave per node. (round-3 proven)
template <int DIN>
__global__ __launch_bounds__(512) void spmm_kernel(
    const __half* __restrict__ ego_h, const int2* __restrict__ row_ptr2,
    const long long* __restrict__ packed, __half* __restrict__ side_out_h) {
  constexpr int LPH = DIN / 8;    // lanes per edge-row (16B fp16 chunks)
  constexpr int NGRP = 64 / LPH;  // edges concurrent

  const int lane = threadIdx.x & 63;
  const int li = lane % LPH;
  const int grp = lane / LPH;
  const int node = (blockIdx.x * blockDim.x + threadIdx.x) >> 6;
  if (node >= N_NODES) return;

  const uint4* __restrict__ ego8 = (const uint4*)ego_h;
  const int2 rp = row_ptr2[node];
  const int start = rp.x;
  const int end = rp.y;

  float s[8] = {0.f, 0.f, 0.f, 0.f, 0.f, 0.f, 0.f, 0.f};

  for (int base = start; base < end; base += 64) {
    const int idx = base + lane;
    long long m = 0;  // col=0, val=0 padding contributes 0
    if (idx < end) m = __builtin_nontemporal_load(packed + idx);
    int mc = (int)m;
    int mv = (int)(m >> 32);
    const int cnt = min(end - base, 64);
    const int kmax = (cnt + NGRP - 1) / NGRP;
    for (int k = 0; k < kmax; ++k) {
      const int src = k * NGRP + grp;
      const int c = __shfl(mc, src, 64);
      const float v = __int_as_float(__shfl(mv, src, 64));
      uint4 raw = ego8[(long)c * LPH + li];
      const __half2* hp = (const __half2*)&raw;
      const float2 f0 = __half22float2(hp[0]);
      const float2 f1 = __half22float2(hp[1]);
      const float2 f2 = __half22float2(hp[2]);
      const float2 f3 = __half22float2(hp[3]);
      s[0] += v * f0.x; s[1] += v * f0.y;
      s[2] += v * f1.x; s[3] += v * f1.y;
      s[4] += v * f2.x; s[5] += v * f2.y;
      s[6] += v * f3.x; s[7] += v * f3.y;
    }
  }

#pragma unroll
  for (int mask = LPH; mask < 64; mask <<= 1) {
#pragma unroll
    for (int r = 0; r < 8; ++r) s[r] += __shfl_xor(s[r], mask, 64);
  }

  if (grp == 0) {
    __half2 p0 = __floats2half2_rn(s[0], s[1]);
    __half2 p1 = __floats2half2_rn(s[2], s[3]);
    __half2 p2 = __floats2half2_rn(s[4], s[5]);
    __half2 p3 = __floats2half2_rn(s[6], s[7]);
    uint4 u;
    u.x = *(unsigned int*)&p0;
    u.y = *(unsigned int*)&p1;
    u.z = *(unsigned int*)&p2;
    u.w = *(unsigned int*)&p3;
    ((uint4*)side_out_h)[(long)node * LPH + li] = u;
  }
}

// ---------------------------------------------------------------------------
// Dense + LN + l2norm (round-3 proven): LDS gang staging, 8 blocks/CU.
template <int DIN, int DOUT, int COL_OFF>
__global__ __launch_bounds__(256, 4) void dense_kernel(
    const __half* __restrict__ ego_h, const __half* __restrict__ side_h,
    const __half* __restrict__ w1t, const float* __restrict__ b1,
    const __half* __restrict__ w2t, const float* __restrict__ b2,
    const float* __restrict__ g1, const float* __restrict__ be1,
    const float* __restrict__ g2, const float* __restrict__ be2,
    __half* __restrict__ ego_h_out, float* __restrict__ out) {
  constexpr int CH = DIN / 8;      // uint4 chunks per node row
  constexpr int G = 64 / CH;       // nodes per staged gang
  constexpr int NPW = 64 / DOUT;   // nodes per dot pass
  constexpr int PASSES = G / NPW;  // dot passes per gang

  const int lane = threadIdx.x & 63;
  const int w = threadIdx.x >> 6;
  const int j = lane % DOUT;
  const int sub = lane / DOUT;
  const int sn = lane / CH;  // node-in-gang this lane stages
  const int sc = lane % CH;  // chunk-in-node this lane stages

  // [wave][xs|xp][G*CH slots] = 4*2*64*16B = 8 KB
  __shared__ uint4 lds[4][2][64];

  const uint4* __restrict__ w1u = (const uint4*)w1t;
  const uint4* __restrict__ w2u = (const uint4*)w2t;
  uint4 wraw1[CH], wraw2[CH];
#pragma unroll
  for (int q = 0; q < CH; ++q) {
    wraw1[q] = w1u[j * CH + q];
    wraw2[q] = w2u[j * CH + q];
  }
  const float bb1 = b1[j], bb2 = b2[j];
  const float gg1 = g1[j], gg2 = g2[j];
  const float bbe1 = be1[j], bbe2 = be2[j];

  const uint4* __restrict__ ego8 = (const uint4*)ego_h;
  const uint4* __restrict__ side8 = (const uint4*)side_h;

  const int waveId = (blockIdx.x * blockDim.x + threadIdx.x) >> 6;
  const int nwaves = (gridDim.x * blockDim.x) >> 6;
  const int ngangs = N_NODES / G;  // exact: 100000 % {8,16} == 0

  uint4 eR, sR;
  if (waveId < ngangs) {
    const size_t b = (size_t)(waveId * G + sn) * CH + sc;
    eR = ego8[b];
    sR = side8[b];
  }

  for (int gang = waveId; gang < ngangs; gang += nwaves) {
    uint4 xsU, xpU;
    {
      const h2* e2 = (const h2*)&eR;
      const h2* s2 = (const h2*)&sR;
      h2* xs2 = (h2*)&xsU;
      h2* xp2 = (h2*)&xpU;
#pragma unroll
      for (int r = 0; r < 4; ++r) {
        xs2[r] = e2[r] + s2[r];
        xp2[r] = e2[r] * s2[r];
      }
    }
    // prior gang's ds_reads fully retired before overwriting the slab
    asm volatile("s_waitcnt lgkmcnt(0)" ::: "memory");
    __builtin_amdgcn_sched_barrier(0);
    lds[w][0][lane] = xsU;
    lds[w][1][lane] = xpU;

    // prefetch next gang into the 8 staging VGPRs (no wait)
    const int gn = gang + nwaves;
    if (gn < ngangs) {
      const size_t b = (size_t)(gn * G + sn) * CH + sc;
      eR = ego8[b];
      sR = side8[b];
    }

    // ds_writes visible to all lanes of this wave before the reads
    asm volatile("s_waitcnt lgkmcnt(0)" ::: "memory");
    __builtin_amdgcn_sched_barrier(0);

#pragma unroll
    for (int p = 0; p < PASSES; ++p) {
      const int nin = p * NPW + sub;
      const int node = gang * G + nin;

      float a1a = bb1, a1b = 0.f, a2a = bb2, a2b = 0.f;
#pragma unroll
      for (int q = 0; q < CH; ++q) {
        uint4 xsq = lds[w][0][nin * CH + q];
        uint4 xpq = lds[w][1][nin * CH + q];
        const h2* xs2 = (const h2*)&xsq;
        const h2* xp2 = (const h2*)&xpq;
        const h2* wq1 = (const h2*)&wraw1[q];
        const h2* wq2 = (const h2*)&wraw2[q];
#pragma unroll
        for (int r = 0; r < 4; ++r) {
#if __has_builtin(__builtin_amdgcn_fdot2)
          if (q & 1) {
            a1b = __builtin_amdgcn_fdot2(xs2[r], wq1[r], a1b, false);
            a2b = __builtin_amdgcn_fdot2(xp2[r], wq2[r], a2b, false);
          } else {
            a1a = __builtin_amdgcn_fdot2(xs2[r], wq1[r], a1a, false);
            a2a = __builtin_amdgcn_fdot2(xp2[r], wq2[r], a2a, false);
          }
#else
          if (q & 1) {
            a1b += (float)xs2[r].x * (float)wq1[r].x +
                   (float)xs2[r].y * (float)wq1[r].y;
            a2b += (float)xp2[r].x * (float)wq2[r].x +
                   (float)xp2[r].y * (float)wq2[r].y;
          } else {
            a1a += (float)xs2[r].x * (float)wq1[r].x +
                   (float)xs2[r].y * (float)wq1[r].y;
            a2a += (float)xp2[r].x * (float)wq2[r].x +
                   (float)xp2[r].y * (float)wq2[r].y;
          }
#endif
        }
      }

      const float acc1 = a1a + a1b;
      const float acc2 = a2a + a2b;
      const float h1 = acc1 > 0.f ? acc1 : 0.01f * acc1;
      const float h2v = acc2 > 0.f ? acc2 : 0.01f * acc2;

      float s1 = h1, q1 = h1 * h1, s2 = h2v, q2 = h2v * h2v;
#pragma unroll
      for (int mask = DOUT / 2; mask > 0; mask >>= 1) {
        s1 += __shfl_xor(s1, mask, DOUT);
        q1 += __shfl_xor(q1, mask, DOUT);
        s2 += __shfl_xor(s2, mask, DOUT);
        q2 += __shfl_xor(q2, mask, DOUT);
      }
      const float m1 = s1 * (1.0f / DOUT);
      const float m2 = s2 * (1.0f / DOUT);
      const float v1 = fmaxf(q1 * (1.0f / DOUT) - m1 * m1, 0.f);
      const float v2 = fmaxf(q2 * (1.0f / DOUT) - m2 * m2, 0.f);
      const float sv = (h1 - m1) * rsqrtf(v1 + LN_EPS) * gg1 + bbe1;
      const float bv = (h2v - m2) * rsqrtf(v2 + LN_EPS) * gg2 + bbe2;
      const float en = sv + bv;

      float ss = en * en;
#pragma unroll
      for (int mask = DOUT / 2; mask > 0; mask >>= 1) {
        ss += __shfl_xor(ss, mask, DOUT);
      }
      const float ov = en / fmaxf(sqrtf(ss), 1e-12f);

      if (ego_h_out) ego_h_out[(long)node * DOUT + j] = __float2half(en);
      out[(long)node * OUT_DIM + COL_OFF + j] = ov;
    }
  }
}

// ---------------------------------------------------------------------------
extern "C" void kernel_launch(void* const* d_in, const int* in_sizes, int n_in,
                              void* d_out, int out_size, void* d_ws,
                              size_t ws_size, hipStream_t stream) {
  const float* emb = (const float*)d_in[0];
  const int* rows = (const int*)d_in[1];
  const int* cols = (const int*)d_in[2];
  const float* vals = (const float*)d_in[3];

  const float* P[3][8];
  for (int k = 0; k < 3; ++k)
    for (int p = 0; p < 8; ++p) P[k][p] = (const float*)d_in[4 + 8 * k + p];

  float* out = (float*)d_out;

  // ---- workspace layout (edge-array capacity depends on path) ----
  const size_t ECAP_PAD = (size_t)NBUCK * PADCAP;  // 3,361,792
  // padded-layout total requirement:
  const size_t need_pad =
      ECAP_PAD * 8 /*packed*/ + ECAP_PAD * 8 /*sideArea(bucketed)*/ +
      (size_t)N_NODES * 64 * 2 * 2 /*emb_h+ego1*/ +
      (size_t)N_NODES * 32 * 2 /*ego2*/ + 13312 * 2 /*weights*/ +
      (size_t)N_NODES * 8 /*row_ptr2*/ + 4096 /*counters+slack*/;
  const int pad_mode = (ws_size >= need_pad) ? 1 : 0;
  const size_t ECAP = pad_mode ? ECAP_PAD : (size_t)N_EDGES;

  char* ws = (char*)d_ws;
  int2* packed = (int2*)ws;                              // ECAP*8
  char* sideArea = ws + ECAP * 8;                        // ECAP*8 region
  __half* side_h = (__half*)sideArea;                    // N*64*2 used
  int2* bucketed = (int2*)sideArea;  // ALIAS: dead before spmm writes side
  __half* emb_h = (__half*)(sideArea + ECAP * 8);        // 12.8 MB
  __half* ego1_h = emb_h + (size_t)N_NODES * 64;         // 12.8 MB
  __half* ego2_h = ego1_h + (size_t)N_NODES * 64;        // 6.4 MB
  __half* wt1_0 = ego2_h + (size_t)N_NODES * 32;         // 4096 halves
  __half* wt2_0 = wt1_0 + 4096;
  __half* wt1_1 = wt2_0 + 4096;  // 2048
  __half* wt2_1 = wt1_1 + 2048;
  __half* wt1_2 = wt2_1 + 2048;  // 512
  __half* wt2_2 = wt1_2 + 512;
  int2* row_ptr2 = (int2*)(wt2_2 + 512);       // N_NODES int2
  int* cursor = (int*)(row_ptr2 + N_NODES);    // NBUCK
  int* gcount = cursor + NBUCK;                // NBUCK (fallback only)
  int* bucket_base = gcount + NBUCK;           // NBUCK (fallback only)

  // ---- CSR build ----
  // cursor (+ gcount for fallback) zeroed in one tiny memset.
  hipMemsetAsync(cursor, 0, 2 * NBUCK * sizeof(int), stream);
  if (!pad_mode) {
    precount_kernel<<<PC_BLOCKS, 256, 0, stream>>>(rows, gcount);
    bucket_scan_kernel<<<1, 256, 0, stream>>>(gcount, bucket_base);
  }
  bucket_pass_kernel<<<BP_BLOCKS, 256, 0, stream>>>(
      rows, cols, vals, bucket_base, cursor, bucketed, pad_mode);
  csr_build_kernel<<<NBUCK, 512, 0, stream>>>(bucketed, bucket_base, cursor,
                                              row_ptr2, packed, pad_mode);

  // ---- prep: convert emb + transposed fp16 weights (one launch) ----
  prep_kernel<<<(N_NODES * 16 + 255) / 256, 256, 0, stream>>>(
      emb, out, emb_h, P[0][0], P[0][2], P[1][0], P[1][2], P[2][0], P[2][2],
      wt1_0, wt2_0, wt1_1, wt2_1, wt1_2, wt2_2);

  const int SPMM_BLOCKS = (N_NODES + 7) / 8;  // wave/node, 512 threads
  const int DENSE_BLOCKS = 2048;              // 8 blocks/CU, all resident

  // ---- layer 0: 64 -> 64 ----
  spmm_kernel<64><<<SPMM_BLOCKS, 512, 0, stream>>>(
      emb_h, row_ptr2, (const long long*)packed, side_h);
  dense_kernel<64, 64, 64><<<DENSE_BLOCKS, 256, 0, stream>>>(
      emb_h, side_h, wt1_0, P[0][1], wt2_0, P[0][3], P[0][4], P[0][5],
      P[0][6], P[0][7], ego1_h, out);

  // ---- layer 1: 64 -> 32 ----
  spmm_kernel<64><<<SPMM_BLOCKS, 512, 0, stream>>>(
      ego1_h, row_ptr2, (const long long*)packed, side_h);
  dense_kernel<64, 32, 128><<<DENSE_BLOCKS, 256, 0, stream>>>(
      ego1_h, side_h, wt1_1, P[1][1], wt2_1, P[1][3], P[1][4], P[1][5],
      P[1][6], P[1][7], ego2_h, out);

  // ---- layer 2: 32 -> 16 ----
  spmm_kernel<32><<<SPMM_BLOCKS, 512, 0, stream>>>(
      ego2_h, row_ptr2, (const long long*)packed, side_h);
  dense_kernel<32, 16, 160><<<DENSE_BLOCKS, 256, 0, stream>>>(
      ego2_h, side_h, wt1_2, P[2][1], wt2_2, P[2][3], P[2][4], P[2][5],
      P[2][6], P[2][7], nullptr, out);
}